// Round 1
// baseline (661.610 us; speedup 1.0000x reference)
//
#include <hip/hip_runtime.h>

// Problem constants (reference: B=128, T=1024, D=512, DOMINANT = {0..15}, q=0.9)
#define B_ 128
#define T_ 1024
#define D_ 512
#define CH 8            // T-chunks for the im reduction
#define TCH (T_ / CH)   // 128

// ---------------------------------------------------------------------------
// Kernel 1: partial sums of g*x over a T-chunk, per (b, d).
// One block = (chunk, b), 512 threads = one per d. Coalesced streaming reads.
// Products in f32 (matches numpy), accumulate in double (kills sum-order
// ambiguity at the quantile boundary).
// ---------------------------------------------------------------------------
__global__ __launch_bounds__(512) void k_im_partial(const float* __restrict__ x,
                                                    const float* __restrict__ g,
                                                    double* __restrict__ part) {
    const int d     = threadIdx.x;   // 0..511
    const int chunk = blockIdx.x;    // 0..CH-1
    const int b     = blockIdx.y;    // 0..B-1
    size_t base = (((size_t)b * T_) + (size_t)chunk * TCH) * D_ + d;
    double s = 0.0;
#pragma unroll 8
    for (int t = 0; t < TCH; ++t) {
        float xv = x[base];
        float gv = g[base];
        s += (double)(xv * gv);   // f32 multiply, f64 accumulate
        base += D_;
    }
    part[(((size_t)b) * CH + chunk) * D_ + d] = s;
}

// ---------------------------------------------------------------------------
// Kernel 2: per batch — combine partials -> im[b,d]; bitonic-sort the 512
// values in LDS; thr = linear-interp quantile at virtual index 0.9*(512-1);
// mask[b,d] = (im > thr) as float 0/1.
// ---------------------------------------------------------------------------
__global__ __launch_bounds__(512) void k_thresh(const double* __restrict__ part,
                                                float* __restrict__ maskf) {
    const int b = blockIdx.x;
    const int d = threadIdx.x;   // 0..511
    double s = 0.0;
#pragma unroll
    for (int c = 0; c < CH; ++c) s += part[(((size_t)b) * CH + c) * D_ + d];
    const float im = (float)(s * (1.0 / (double)T_));   // /1024 is exact

    __shared__ float sm[D_];
    sm[d] = im;
    __syncthreads();

    // In-place bitonic sort, ascending. 512 elements, 512 threads.
    for (int k = 2; k <= D_; k <<= 1) {
        for (int j = k >> 1; j > 0; j >>= 1) {
            const int ixj = d ^ j;
            if (ixj > d) {
                const float a = sm[d];
                const float c = sm[ixj];
                const bool up = ((d & k) == 0);
                if ((a > c) == up) { sm[d] = c; sm[ixj] = a; }
            }
            __syncthreads();
        }
    }

    // q*(n-1) = 0.9*511 = 459.9 -> lerp between ranks 459 and 460
    const float lo  = sm[459];
    const float hi  = sm[460];
    const float thr = lo + 0.9f * (hi - lo);
    maskf[(size_t)b * D_ + d] = (im > thr) ? 1.0f : 0.0f;
}

// ---------------------------------------------------------------------------
// Kernel 3: output.
//   non-dominant: out = x                       (sg + sr == x exactly)
//   dominant:     out = x*(1-mb) + m*x*mb + (1-m)*x[p]*mp
// blockIdx.y = batch -> the dominant/non-dominant branch is block-uniform.
// float4 everywhere (16 B/lane).
// ---------------------------------------------------------------------------
__global__ __launch_bounds__(256) void k_out(const float* __restrict__ x,
                                             const float* __restrict__ maskf,
                                             const float* __restrict__ mix,
                                             const int* __restrict__ scen,
                                             const int* __restrict__ pidx,
                                             float* __restrict__ out) {
    const int b = blockIdx.y;
    const size_t r   = (size_t)blockIdx.x * blockDim.x + threadIdx.x;  // float4 unit within batch
    const size_t idx = (size_t)b * (size_t)(T_ * D_ / 4) + r;

    const float4* x4 = (const float4*)x;
    const float4  xv = x4[idx];
    float4 o;

    if (scen[b] < 16) {   // dominant (is_dominant == scenario in {0..15})
        const int   p  = pidx[b];
        const float m  = mix[b];
        const float om = 1.0f - m;
        const int    d4 = (int)(r & (D_ / 4 - 1));   // 0..127
        const size_t t  = r >> 7;                    // r / (D/4)
        const float4 mb = ((const float4*)(maskf + (size_t)b * D_))[d4];
        const float4 mp = ((const float4*)(maskf + (size_t)p * D_))[d4];
        const float4 xp = x4[((size_t)p * T_ + t) * (size_t)(D_ / 4) + d4];
        o.x = xv.x * (1.0f - mb.x) + (m * xv.x) * mb.x + (om * xp.x) * mp.x;
        o.y = xv.y * (1.0f - mb.y) + (m * xv.y) * mb.y + (om * xp.y) * mp.y;
        o.z = xv.z * (1.0f - mb.z) + (m * xv.z) * mb.z + (om * xp.z) * mp.z;
        o.w = xv.w * (1.0f - mb.w) + (m * xv.w) * mb.w + (om * xp.w) * mp.w;
    } else {
        o = xv;
    }
    ((float4*)out)[idx] = o;
}

// ---------------------------------------------------------------------------
extern "C" void kernel_launch(void* const* d_in, const int* in_sizes, int n_in,
                              void* d_out, int out_size, void* d_ws, size_t ws_size,
                              hipStream_t stream) {
    const float* x    = (const float*)d_in[0];   // (B,T,D) f32
    const float* g    = (const float*)d_in[1];   // (B,T,D) f32
    const float* mix  = (const float*)d_in[2];   // (B,)   f32
    const int*   scen = (const int*)d_in[3];     // (B,)   int32 (JAX demotes int64)
    const int*   pidx = (const int*)d_in[4];     // (B,)   int32
    // d_in[5] = is_dominant (bool) -- unused; derived as scen < 16
    float* out = (float*)d_out;

    double* part  = (double*)d_ws;                                   // B*CH*D doubles = 4 MiB
    float*  maskf = (float*)((char*)d_ws +
                             (size_t)B_ * CH * D_ * sizeof(double)); // B*D floats = 256 KiB

    dim3 g1(CH, B_);
    k_im_partial<<<g1, 512, 0, stream>>>(x, g, part);

    k_thresh<<<B_, D_, 0, stream>>>(part, maskf);

    dim3 g3(T_ * D_ / 4 / 256, B_);
    k_out<<<g3, 256, 0, stream>>>(x, maskf, mix, scen, pidx, out);
}